// Round 3
// baseline (335.305 us; speedup 1.0000x reference)
//
#include <hip/hip_runtime.h>

// LinearModel: y[b,l], logits[b,c,l] from per-label 2-layer MLP.
// B=32 C=64 E=512 L=100. Dominant cost: 100x GEMM [2048x512]x[512x512] (~107 GFLOP).
// Strategy: bf16 MFMA (threshold 0.84 tolerates bf16). Pre-kernels convert
// c_emb and transpose+convert W1 into swizzled bf16 tile images in ws so the
// GEMM stages via linear global_load_lds dwordx4 (swizzle pre-applied in the
// global image per m173: gload_lds writes linearly, so source carries the swizzle).

typedef unsigned short u16;
typedef unsigned int   u32;
typedef __attribute__((ext_vector_type(8))) short short8;
typedef __attribute__((ext_vector_type(4))) float f32x4;
typedef __attribute__((address_space(1))) const u32 as1_u32;
typedef __attribute__((address_space(3))) u32 as3_u32;

#define E_DIM 512
#define L_DIM 100
#define Y_SZ  3200            // 32*100
#define LG_OFF 3200

__device__ __forceinline__ u16 f2bf(float f) {
  union { float f; u32 u; } v; v.f = f;
  u32 u = v.u;
  u32 r = u + 0x7fffu + ((u >> 16) & 1u);   // round-to-nearest-even
  return (u16)(r >> 16);
}

// ---------------- pre-kernel 1: c_emb f32 -> swizzled bf16 tile image -------
// Tile (mt, kt): 128 rows (bc) x 64 cols (e). ushort idx within tile:
//   r*64 + (c ^ ((r&7)<<3))   (XOR swizzle, 8-elem granularity -> 16B chunks)
__global__ __launch_bounds__(256) void conv_a_kernel(const float* __restrict__ src,
                                                     u16* __restrict__ dst) {
  int g = blockIdx.x * 256 + threadIdx.x;       // 131072 threads
  int base = g << 3;                             // 8 elems each
  int bc = base >> 9;
  int e  = base & 511;
  const float4* p = (const float4*)(src + base);
  float4 v0 = p[0];
  float4 v1 = p[1];
  union { u16 h[8]; uint4 q; } u;
  u.h[0]=f2bf(v0.x); u.h[1]=f2bf(v0.y); u.h[2]=f2bf(v0.z); u.h[3]=f2bf(v0.w);
  u.h[4]=f2bf(v1.x); u.h[5]=f2bf(v1.y); u.h[6]=f2bf(v1.z); u.h[7]=f2bf(v1.w);
  int mt = bc >> 7, kt = e >> 6, r = bc & 127, c = e & 63;
  int idx = (mt*8 + kt)*8192 + r*64 + (c ^ ((r & 7) << 3));
  *(uint4*)(dst + idx) = u.q;
}

// ---------------- pre-kernel 2: W1[l][e][h] -> W1T[l][h][e] bf16 tiles ------
// Dest tile (l, ht128, kt): 128 rows (h) x 64 cols (e), same swizzle as A.
__global__ __launch_bounds__(256) void conv_w_kernel(const float* __restrict__ W1,
                                                     u16* __restrict__ dst) {
  __shared__ float T[64][65];                    // [h][e], +1 pad
  int blk = blockIdx.x;                          // 100*64 = 6400
  int l = blk / 64;
  int rem = blk - l*64;
  int et = rem >> 3, ht = rem & 7;               // 64x64 tile of (e,h)
  int tid = threadIdx.x;
  int e0 = et*64, h0 = ht*64;
  const float* basep = W1 + (size_t)l * (E_DIM*E_DIM);
  int ecol = tid >> 4;                           // 0..15
  int hq = (tid & 15) * 4;
  #pragma unroll
  for (int i = 0; i < 4; ++i) {
    int e = ecol + i*16;
    float4 v = *(const float4*)(basep + (size_t)(e0 + e)*E_DIM + h0 + hq);
    T[hq+0][e] = v.x; T[hq+1][e] = v.y; T[hq+2][e] = v.z; T[hq+3][e] = v.w;
  }
  __syncthreads();
  int rl = tid & 63, cg = tid >> 6;
  int hgl = h0 + rl;
  int ht128 = hgl >> 7, r = hgl & 127;
  size_t tbase = ((size_t)(l*4 + ht128)*8 + et) * 8192;
  #pragma unroll
  for (int s = 0; s < 2; ++s) {
    int c0 = cg*16 + s*8;
    union { u16 h[8]; uint4 q; } u;
    #pragma unroll
    for (int j = 0; j < 8; ++j) u.h[j] = f2bf(T[rl][c0 + j]);
    size_t idx = tbase + r*64 + (c0 ^ ((r & 7) << 3));
    *(uint4*)(dst + idx) = u.q;
  }
}

// ---------------- main fused GEMM ------------------------------------------
// Block: (mt, l). 128 bc-rows x 128 h-cols per h-block, 4 h-blocks, K=512 in
// 8x64 double-buffered LDS steps via global_load_lds. 4 waves, each 64x64.
__global__ __launch_bounds__(256, 2) void gemm_kernel(
    const u16* __restrict__ Aws, const u16* __restrict__ Wws,
    const float* __restrict__ c_pred, const float* __restrict__ b1,
    const float* __restrict__ W2, const float* __restrict__ b2,
    float* __restrict__ out)
{
  __shared__ __align__(16) u16 As[2][8192];      // 32 KB
  __shared__ __align__(16) u16 Bs[2][8192];      // 32 KB  (total 64 KB)

  const int mt  = blockIdx.x;                    // 0..15
  const int l   = blockIdx.y;                    // 0..99
  const int tid = threadIdx.x;
  const int wid = tid >> 6;
  const int lane = tid & 63;
  const int wr = wid >> 1;                       // wave row (0..1) -> 64 rows
  const int wc = wid & 1;                        // wave col (0..1) -> 64 cols
  const int lr = lane & 15;                      // M-row / N-col within 16
  const int lgp = lane >> 4;                     // k-group 0..3

  float wacc[4][4];
  #pragma unroll
  for (int m = 0; m < 4; ++m)
    #pragma unroll
    for (int r = 0; r < 4; ++r) wacc[m][r] = 0.f;

  auto stage = [&](int buf, int hb, int kt) {
    const u16* asrc = Aws + (mt*8 + kt)*8192;
    const u16* bsrc = Wws + ((l*4 + hb)*8 + kt)*8192;
    #pragma unroll
    for (int i = 0; i < 4; ++i) {
      int chunk = wid*4 + i;                     // 16 x 1KB chunks per tile
      int uoff = chunk*512;                      // ushort offset (wave-uniform)
      int goff = uoff + lane*8;                  // per-lane 16B
      __builtin_amdgcn_global_load_lds((as1_u32*)(asrc + goff),
                                       (as3_u32*)(&As[buf][uoff]), 16, 0, 0);
      __builtin_amdgcn_global_load_lds((as1_u32*)(bsrc + goff),
                                       (as3_u32*)(&Bs[buf][uoff]), 16, 0, 0);
    }
  };

  stage(0, 0, 0);
  __syncthreads();                               // drains vmcnt before barrier
  int cur = 0;
  const f32x4 zero4 = {0.f, 0.f, 0.f, 0.f};

  for (int hb = 0; hb < 4; ++hb) {
    f32x4 acc[4][4];
    #pragma unroll
    for (int mi = 0; mi < 4; ++mi)
      #pragma unroll
      for (int ni = 0; ni < 4; ++ni) acc[mi][ni] = zero4;

    for (int kt = 0; kt < 8; ++kt) {
      int nkt = kt + 1, nhb = hb;
      if (nkt == 8) { nkt = 0; ++nhb; }
      if (nhb < 4) stage(cur ^ 1, nhb, nkt);     // prefetch overlaps compute

      #pragma unroll
      for (int ks = 0; ks < 2; ++ks) {
        short8 af[4], bfr[4];
        #pragma unroll
        for (int mi = 0; mi < 4; ++mi) {
          int row = wr*64 + mi*16 + lr;
          int col = ks*32 + lgp*8;
          af[mi] = *(const short8*)&As[cur][row*64 + (col ^ ((row & 7) << 3))];
        }
        #pragma unroll
        for (int ni = 0; ni < 4; ++ni) {
          int row = wc*64 + ni*16 + lr;
          int col = ks*32 + lgp*8;
          bfr[ni] = *(const short8*)&Bs[cur][row*64 + (col ^ ((row & 7) << 3))];
        }
        #pragma unroll
        for (int mi = 0; mi < 4; ++mi)
          #pragma unroll
          for (int ni = 0; ni < 4; ++ni)
            acc[mi][ni] = __builtin_amdgcn_mfma_f32_16x16x32_bf16(
                af[mi], bfr[ni], acc[mi][ni], 0, 0, 0);
      }
      __syncthreads();                           // next buffer ready after this
      cur ^= 1;
    }

    // fused epilogue for this h-block: bias + ReLU + dot(W2), lane-local.
    // C/D layout (m89): col = lane&15, row = (lane>>4)*4 + reg.
    #pragma unroll
    for (int ni = 0; ni < 4; ++ni) {
      int h = hb*128 + wc*64 + ni*16 + lr;
      float b1v = b1[l*E_DIM + h];
      float w2v = W2[l*E_DIM + h];
      #pragma unroll
      for (int mi = 0; mi < 4; ++mi)
        #pragma unroll
        for (int r = 0; r < 4; ++r) {
          float v = acc[mi][ni][r] + b1v;
          v = fmaxf(v, 0.f);
          wacc[mi][r] = fmaf(v, w2v, wacc[mi][r]);
        }
    }
  }

  // reduce wacc over the 16 column-lanes (cols live in lane&15)
  #pragma unroll
  for (int m = 0; m < 4; ++m)
    #pragma unroll
    for (int r = 0; r < 4; ++r) {
      float s = wacc[m][r];
      s += __shfl_xor(s, 1);
      s += __shfl_xor(s, 2);
      s += __shfl_xor(s, 4);
      s += __shfl_xor(s, 8);
      wacc[m][r] = s;
    }

  float (*w_part)[128] = (float(*)[128])&As[0][0];  // reuse LDS (compute done)
  if (lr == 0) {
    #pragma unroll
    for (int m = 0; m < 4; ++m)
      #pragma unroll
      for (int r = 0; r < 4; ++r)
        w_part[wc][wr*64 + m*16 + lgp*4 + r] = wacc[m][r];
  }
  __syncthreads();

  if (tid < 128) {
    int bcg = mt*128 + tid;
    float w = w_part[0][tid] + w_part[1][tid] + b2[l];
    float lgt = w * c_pred[bcg];
    out[LG_OFF + bcg*L_DIM + l] = lgt;
    float s = lgt;
    s += __shfl_down(s, 32);
    s += __shfl_down(s, 16);
    s += __shfl_down(s, 8);
    s += __shfl_down(s, 4);
    s += __shfl_down(s, 2);
    s += __shfl_down(s, 1);
    if (lane == 0) out[(bcg >> 6)*L_DIM + l] = s;   // y[b,l]
  }
}

// ---------------- fallback (ws too small): correct fp32 path ---------------
__global__ __launch_bounds__(256) void naive_kernel(
    const float* __restrict__ c_emb, const float* __restrict__ c_pred,
    const float* __restrict__ W1, const float* __restrict__ b1,
    const float* __restrict__ W2, const float* __restrict__ b2,
    float* __restrict__ out)
{
  __shared__ float a_lds[16][512];
  __shared__ float wsum[4][16];
  int l = blockIdx.y;
  int rt = blockIdx.x;                           // 128 tiles of 16 rows
  int tid = threadIdx.x, lane = tid & 63, wid = tid >> 6;
  int row0 = rt * 16;
  #pragma unroll
  for (int i = 0; i < 8; ++i) {
    int flat = i*1024 + tid*4;
    int r = flat >> 9, e = flat & 511;
    *(float4*)&a_lds[r][e] = *(const float4*)&c_emb[(size_t)(row0 + r)*E_DIM + e];
  }
  __syncthreads();
  int h0 = tid, h1 = tid + 256;
  const float* w1b = W1 + (size_t)l * (E_DIM*E_DIM);
  float acc0[16], acc1[16];
  #pragma unroll
  for (int r = 0; r < 16; ++r) { acc0[r] = 0.f; acc1[r] = 0.f; }
  for (int e = 0; e < E_DIM; ++e) {
    float wa = w1b[(size_t)e*E_DIM + h0];
    float wb = w1b[(size_t)e*E_DIM + h1];
    #pragma unroll
    for (int r = 0; r < 16; ++r) {
      float a = a_lds[r][e];
      acc0[r] = fmaf(a, wa, acc0[r]);
      acc1[r] = fmaf(a, wb, acc1[r]);
    }
  }
  float b1a = b1[l*E_DIM + h0], b1c = b1[l*E_DIM + h1];
  float w2a = W2[l*E_DIM + h0], w2c = W2[l*E_DIM + h1];
  float part[16];
  #pragma unroll
  for (int r = 0; r < 16; ++r) {
    float v0 = fmaxf(acc0[r] + b1a, 0.f) * w2a;
    float v1 = fmaxf(acc1[r] + b1c, 0.f) * w2c;
    part[r] = v0 + v1;
  }
  #pragma unroll
  for (int r = 0; r < 16; ++r) {
    float s = part[r];
    s += __shfl_down(s, 32); s += __shfl_down(s, 16); s += __shfl_down(s, 8);
    s += __shfl_down(s, 4);  s += __shfl_down(s, 2);  s += __shfl_down(s, 1);
    if (lane == 0) wsum[wid][r] = s;
  }
  __syncthreads();
  if (tid < 16) {
    float w = wsum[0][tid] + wsum[1][tid] + wsum[2][tid] + wsum[3][tid] + b2[l];
    int bc = row0 + tid;
    float lgt = w * c_pred[bc];
    out[LG_OFF + bc*L_DIM + l] = lgt;
    atomicAdd(&out[(bc >> 6)*L_DIM + l], lgt);
  }
}

extern "C" void kernel_launch(void* const* d_in, const int* in_sizes, int n_in,
                              void* d_out, int out_size, void* d_ws, size_t ws_size,
                              hipStream_t stream) {
  const float* c_emb  = (const float*)d_in[0];
  const float* c_pred = (const float*)d_in[1];
  const float* W1     = (const float*)d_in[2];
  const float* b1     = (const float*)d_in[3];
  const float* W2     = (const float*)d_in[4];
  const float* b2     = (const float*)d_in[5];
  float* out = (float*)d_out;

  const size_t nA = 1048576;       // 32*64*512
  const size_t nW = 26214400;      // 100*512*512
  const size_t need = 2*nA + 2*nW; // bf16 copies: ~54.5 MB

  if (ws_size >= need) {
    u16* Aws = (u16*)d_ws;
    u16* Wws = (u16*)d_ws + nA;
    conv_a_kernel<<<512, 256, 0, stream>>>(c_emb, Aws);
    conv_w_kernel<<<6400, 256, 0, stream>>>(W1, Wws);
    gemm_kernel<<<dim3(16, 100), 256, 0, stream>>>(Aws, Wws, c_pred, b1, W2, b2, out);
  } else {
    hipMemsetAsync(out, 0, Y_SZ*sizeof(float), stream);  // y accumulated via atomics
    naive_kernel<<<dim3(128, 100), 256, 0, stream>>>(c_emb, c_pred, W1, b1, W2, b2, out);
  }
}

// Round 9
// 323.765 us; speedup vs baseline: 1.0356x; 1.0356x over previous
//
#include <hip/hip_runtime.h>

// LinearModel: y[b,l], logits[b,c,l] from per-label 2-layer MLP.
// B=32 C=64 E=512 L=100. Dominant cost: 100x GEMM [2048x512]x[512x512] (~107 GFLOP)
// == one GEMM M=2048 K=512 N=51200. bf16 MFMA path (absmax 0.25 vs thr 0.84).
// R3 changes: (1) conv_w rewritten for coalesced 1KB/wave stores (was 16B@128B
// stride -> ~130us); (2) gemm XCD-chunk swizzle so the 16 m-blocks sharing an
// l-panel colocate on one XCD's L2 (FETCH 210MB -> ~75MB expected).

typedef unsigned short u16;
typedef unsigned int   u32;
typedef __attribute__((ext_vector_type(8))) short short8;
typedef __attribute__((ext_vector_type(4))) float f32x4;
typedef __attribute__((address_space(1))) const u32 as1_u32;
typedef __attribute__((address_space(3))) u32 as3_u32;

#define E_DIM 512
#define L_DIM 100
#define Y_SZ  3200            // 32*100
#define LG_OFF 3200

__device__ __forceinline__ u16 f2bf(float f) {
  union { float f; u32 u; } v; v.f = f;
  u32 u = v.u;
  u32 r = u + 0x7fffu + ((u >> 16) & 1u);   // round-to-nearest-even
  return (u16)(r >> 16);
}

// ---------------- pre-kernel 1: c_emb f32 -> swizzled bf16 tile image -------
// Tile (mt, kt): 128 rows (bc) x 64 cols (e). ushort idx within tile:
//   r*64 + (c ^ ((r&7)<<3))   (XOR swizzle, 8-elem granularity -> 16B chunks)
__global__ __launch_bounds__(256) void conv_a_kernel(const float* __restrict__ src,
                                                     u16* __restrict__ dst) {
  int g = blockIdx.x * 256 + threadIdx.x;       // 131072 threads
  int base = g << 3;                             // 8 elems each
  int bc = base >> 9;
  int e  = base & 511;
  const float4* p = (const float4*)(src + base);
  float4 v0 = p[0];
  float4 v1 = p[1];
  union { u16 h[8]; uint4 q; } u;
  u.h[0]=f2bf(v0.x); u.h[1]=f2bf(v0.y); u.h[2]=f2bf(v0.z); u.h[3]=f2bf(v0.w);
  u.h[4]=f2bf(v1.x); u.h[5]=f2bf(v1.y); u.h[6]=f2bf(v1.z); u.h[7]=f2bf(v1.w);
  int mt = bc >> 7, kt = e >> 6, r = bc & 127, c = e & 63;
  int idx = (mt*8 + kt)*8192 + r*64 + (c ^ ((r & 7) << 3));
  *(uint4*)(dst + idx) = u.q;
}

// ---------------- pre-kernel 2: W1[l][e][h] -> W1T[l][h][e] bf16 tiles ------
// Dest tile (l, ht128, kt): 128 rows (h) x 64 cols (e), same swizzle as A.
// R3: LDS held as T[e][h]; writes are 1KB-contiguous per wave (8 lanes cover
// one 128B dest row, 8 rows per wave). All LDS phases 2-way aliased = free.
__global__ __launch_bounds__(256) void conv_w_kernel(const float* __restrict__ W1,
                                                     u16* __restrict__ dst) {
  __shared__ float T[64][65];                    // [e_local][h_local], +1 pad
  int blk = blockIdx.x;                          // 100*64 = 6400
  int l = blk >> 6;
  int rem = blk & 63;
  int et = rem >> 3, ht = rem & 7;               // 64x64 tile of (e,h)
  int tid = threadIdx.x;
  int e0 = et*64, h0 = ht*64;
  const float* basep = W1 + (size_t)l * (E_DIM*E_DIM);
  int erow = tid >> 4;                           // 0..15
  int hq = (tid & 15) * 4;                       // 0..60
  #pragma unroll
  for (int i = 0; i < 4; ++i) {
    int e = erow + i*16;
    float4 v = *(const float4*)(basep + (size_t)(e0 + e)*E_DIM + h0 + hq);
    T[e][hq+0] = v.x; T[e][hq+1] = v.y; T[e][hq+2] = v.z; T[e][hq+3] = v.w;
  }
  __syncthreads();
  int rl_h = tid >> 3;                           // 0..31
  int c0 = (tid & 7) * 8;                        // e_local chunk
  size_t tbase = ((size_t)(l*4 + (ht >> 1))*8 + et) * 8192;
  #pragma unroll
  for (int p = 0; p < 2; ++p) {
    int r_local = p*32 + rl_h;                   // h within 64-tile
    union { u16 h[8]; uint4 q; } u;
    #pragma unroll
    for (int j = 0; j < 8; ++j) u.h[j] = f2bf(T[c0 + j][r_local]);
    int r = ((ht & 1) << 6) + r_local;           // h within 128-row dest tile
    size_t idx = tbase + r*64 + (c0 ^ ((r & 7) << 3));
    *(uint4*)(dst + idx) = u.q;
  }
}

// ---------------- main fused GEMM ------------------------------------------
// Block: (mt, l) via XCD-chunk-swizzled 1D grid. 128 bc-rows x 128 h-cols per
// h-block, 4 h-blocks, K=512 in 8x64 double-buffered LDS steps via
// global_load_lds. 4 waves, each 64x64.
__global__ __launch_bounds__(256, 2) void gemm_kernel(
    const u16* __restrict__ Aws, const u16* __restrict__ Wws,
    const float* __restrict__ c_pred, const float* __restrict__ b1,
    const float* __restrict__ W2, const float* __restrict__ b2,
    float* __restrict__ out)
{
  __shared__ __align__(16) u16 As[2][8192];      // 32 KB
  __shared__ __align__(16) u16 Bs[2][8192];      // 32 KB  (total 64 KB)

  // XCD swizzle: 1600 blocks, 1600%8==0 -> bijective chunk map. Chunk of 200
  // consecutive swz ids = ~12.5 l-panels exclusive to one XCD's L2.
  const int wg  = blockIdx.x;
  const int swz = (wg & 7) * 200 + (wg >> 3);
  const int l   = swz >> 4;                      // 0..99
  const int mt  = swz & 15;                      // 0..15
  const int tid = threadIdx.x;
  const int wid = tid >> 6;
  const int lane = tid & 63;
  const int wr = wid >> 1;                       // wave row (0..1) -> 64 rows
  const int wc = wid & 1;                        // wave col (0..1) -> 64 cols
  const int lr = lane & 15;                      // M-row / N-col within 16
  const int lgp = lane >> 4;                     // k-group 0..3

  float wacc[4][4];
  #pragma unroll
  for (int m = 0; m < 4; ++m)
    #pragma unroll
    for (int r = 0; r < 4; ++r) wacc[m][r] = 0.f;

  auto stage = [&](int buf, int hb, int kt) {
    const u16* asrc = Aws + (mt*8 + kt)*8192;
    const u16* bsrc = Wws + ((l*4 + hb)*8 + kt)*8192;
    #pragma unroll
    for (int i = 0; i < 4; ++i) {
      int chunk = wid*4 + i;                     // 16 x 1KB chunks per tile
      int uoff = chunk*512;                      // ushort offset (wave-uniform)
      int goff = uoff + lane*8;                  // per-lane 16B
      __builtin_amdgcn_global_load_lds((as1_u32*)(asrc + goff),
                                       (as3_u32*)(&As[buf][uoff]), 16, 0, 0);
      __builtin_amdgcn_global_load_lds((as1_u32*)(bsrc + goff),
                                       (as3_u32*)(&Bs[buf][uoff]), 16, 0, 0);
    }
  };

  stage(0, 0, 0);
  __syncthreads();                               // drains vmcnt before barrier
  int cur = 0;
  const f32x4 zero4 = {0.f, 0.f, 0.f, 0.f};

  for (int hb = 0; hb < 4; ++hb) {
    f32x4 acc[4][4];
    #pragma unroll
    for (int mi = 0; mi < 4; ++mi)
      #pragma unroll
      for (int ni = 0; ni < 4; ++ni) acc[mi][ni] = zero4;

    for (int kt = 0; kt < 8; ++kt) {
      int nkt = kt + 1, nhb = hb;
      if (nkt == 8) { nkt = 0; ++nhb; }
      if (nhb < 4) stage(cur ^ 1, nhb, nkt);     // prefetch overlaps compute

      #pragma unroll
      for (int ks = 0; ks < 2; ++ks) {
        short8 af[4], bfr[4];
        #pragma unroll
        for (int mi = 0; mi < 4; ++mi) {
          int row = wr*64 + mi*16 + lr;
          int col = ks*32 + lgp*8;
          af[mi] = *(const short8*)&As[cur][row*64 + (col ^ ((row & 7) << 3))];
        }
        #pragma unroll
        for (int ni = 0; ni < 4; ++ni) {
          int row = wc*64 + ni*16 + lr;
          int col = ks*32 + lgp*8;
          bfr[ni] = *(const short8*)&Bs[cur][row*64 + (col ^ ((row & 7) << 3))];
        }
        #pragma unroll
        for (int mi = 0; mi < 4; ++mi)
          #pragma unroll
          for (int ni = 0; ni < 4; ++ni)
            acc[mi][ni] = __builtin_amdgcn_mfma_f32_16x16x32_bf16(
                af[mi], bfr[ni], acc[mi][ni], 0, 0, 0);
      }
      __syncthreads();                           // next buffer ready after this
      cur ^= 1;
    }

    // fused epilogue for this h-block: bias + ReLU + dot(W2), lane-local.
    // C/D layout (m89): col = lane&15, row = (lane>>4)*4 + reg.
    #pragma unroll
    for (int ni = 0; ni < 4; ++ni) {
      int h = hb*128 + wc*64 + ni*16 + lr;
      float b1v = b1[l*E_DIM + h];
      float w2v = W2[l*E_DIM + h];
      #pragma unroll
      for (int mi = 0; mi < 4; ++mi)
        #pragma unroll
        for (int r = 0; r < 4; ++r) {
          float v = acc[mi][ni][r] + b1v;
          v = fmaxf(v, 0.f);
          wacc[mi][r] = fmaf(v, w2v, wacc[mi][r]);
        }
    }
  }

  // reduce wacc over the 16 column-lanes (cols live in lane&15)
  #pragma unroll
  for (int m = 0; m < 4; ++m)
    #pragma unroll
    for (int r = 0; r < 4; ++r) {
      float s = wacc[m][r];
      s += __shfl_xor(s, 1);
      s += __shfl_xor(s, 2);
      s += __shfl_xor(s, 4);
      s += __shfl_xor(s, 8);
      wacc[m][r] = s;
    }

  float (*w_part)[128] = (float(*)[128])&As[0][0];  // reuse LDS (compute done)
  if (lr == 0) {
    #pragma unroll
    for (int m = 0; m < 4; ++m)
      #pragma unroll
      for (int r = 0; r < 4; ++r)
        w_part[wc][wr*64 + m*16 + lgp*4 + r] = wacc[m][r];
  }
  __syncthreads();

  if (tid < 128) {
    int bcg = mt*128 + tid;
    float w = w_part[0][tid] + w_part[1][tid] + b2[l];
    float lgt = w * c_pred[bcg];
    out[LG_OFF + bcg*L_DIM + l] = lgt;
    float s = lgt;
    s += __shfl_down(s, 32);
    s += __shfl_down(s, 16);
    s += __shfl_down(s, 8);
    s += __shfl_down(s, 4);
    s += __shfl_down(s, 2);
    s += __shfl_down(s, 1);
    if (lane == 0) out[(bcg >> 6)*L_DIM + l] = s;   // y[b,l]
  }
}

// ---------------- fallback (ws too small): correct fp32 path ---------------
__global__ __launch_bounds__(256) void naive_kernel(
    const float* __restrict__ c_emb, const float* __restrict__ c_pred,
    const float* __restrict__ W1, const float* __restrict__ b1,
    const float* __restrict__ W2, const float* __restrict__ b2,
    float* __restrict__ out)
{
  __shared__ float a_lds[16][512];
  __shared__ float wsum[4][16];
  int l = blockIdx.y;
  int rt = blockIdx.x;                           // 128 tiles of 16 rows
  int tid = threadIdx.x, lane = tid & 63, wid = tid >> 6;
  int row0 = rt * 16;
  #pragma unroll
  for (int i = 0; i < 8; ++i) {
    int flat = i*1024 + tid*4;
    int r = flat >> 9, e = flat & 511;
    *(float4*)&a_lds[r][e] = *(const float4*)&c_emb[(size_t)(row0 + r)*E_DIM + e];
  }
  __syncthreads();
  int h0 = tid, h1 = tid + 256;
  const float* w1b = W1 + (size_t)l * (E_DIM*E_DIM);
  float acc0[16], acc1[16];
  #pragma unroll
  for (int r = 0; r < 16; ++r) { acc0[r] = 0.f; acc1[r] = 0.f; }
  for (int e = 0; e < E_DIM; ++e) {
    float wa = w1b[(size_t)e*E_DIM + h0];
    float wb = w1b[(size_t)e*E_DIM + h1];
    #pragma unroll
    for (int r = 0; r < 16; ++r) {
      float a = a_lds[r][e];
      acc0[r] = fmaf(a, wa, acc0[r]);
      acc1[r] = fmaf(a, wb, acc1[r]);
    }
  }
  float b1a = b1[l*E_DIM + h0], b1c = b1[l*E_DIM + h1];
  float w2a = W2[l*E_DIM + h0], w2c = W2[l*E_DIM + h1];
  float part[16];
  #pragma unroll
  for (int r = 0; r < 16; ++r) {
    float v0 = fmaxf(acc0[r] + b1a, 0.f) * w2a;
    float v1 = fmaxf(acc1[r] + b1c, 0.f) * w2c;
    part[r] = v0 + v1;
  }
  #pragma unroll
  for (int r = 0; r < 16; ++r) {
    float s = part[r];
    s += __shfl_down(s, 32); s += __shfl_down(s, 16); s += __shfl_down(s, 8);
    s += __shfl_down(s, 4);  s += __shfl_down(s, 2);  s += __shfl_down(s, 1);
    if (lane == 0) wsum[wid][r] = s;
  }
  __syncthreads();
  if (tid < 16) {
    float w = wsum[0][tid] + wsum[1][tid] + wsum[2][tid] + wsum[3][tid] + b2[l];
    int bc = row0 + tid;
    float lgt = w * c_pred[bc];
    out[LG_OFF + bc*L_DIM + l] = lgt;
    atomicAdd(&out[(bc >> 6)*L_DIM + l], lgt);
  }
}

extern "C" void kernel_launch(void* const* d_in, const int* in_sizes, int n_in,
                              void* d_out, int out_size, void* d_ws, size_t ws_size,
                              hipStream_t stream) {
  const float* c_emb  = (const float*)d_in[0];
  const float* c_pred = (const float*)d_in[1];
  const float* W1     = (const float*)d_in[2];
  const float* b1     = (const float*)d_in[3];
  const float* W2     = (const float*)d_in[4];
  const float* b2     = (const float*)d_in[5];
  float* out = (float*)d_out;

  const size_t nA = 1048576;       // 32*64*512
  const size_t nW = 26214400;      // 100*512*512
  const size_t need = 2*nA + 2*nW; // bf16 copies: ~54.5 MB

  if (ws_size >= need) {
    u16* Aws = (u16*)d_ws;
    u16* Wws = (u16*)d_ws + nA;
    conv_a_kernel<<<512, 256, 0, stream>>>(c_emb, Aws);
    conv_w_kernel<<<6400, 256, 0, stream>>>(W1, Wws);
    gemm_kernel<<<1600, 256, 0, stream>>>(Aws, Wws, c_pred, b1, W2, b2, out);
  } else {
    hipMemsetAsync(out, 0, Y_SZ*sizeof(float), stream);  // y accumulated via atomics
    naive_kernel<<<dim3(128, 100), 256, 0, stream>>>(c_emb, c_pred, W1, b1, W2, b2, out);
  }
}

// Round 10
// 318.342 us; speedup vs baseline: 1.0533x; 1.0170x over previous
//
#include <hip/hip_runtime.h>

// LinearModel: y[b,l], logits[b,c,l] from per-label 2-layer MLP.
// B=32 C=64 E=512 L=100. One GEMM M=2048 K=512 N=51200 (~107 GFLOP), bf16 MFMA.
// R9: gemm occupancy fix. R3 measured MfmaUtil 26.8%, Occ 17.9% with 4-wave
// blocks; per-kt vmcnt(0)+barrier drain only covered by resident waves (m114).
// -> 512-thr blocks (8 waves, 2x4, wave tile 64x32), same LDS/sync/swizzle:
// 2 blocks/CU x 8 waves = 16 waves/CU. conv kernels + image format unchanged.

typedef unsigned short u16;
typedef unsigned int   u32;
typedef __attribute__((ext_vector_type(8))) short short8;
typedef __attribute__((ext_vector_type(4))) float f32x4;
typedef __attribute__((address_space(1))) const u32 as1_u32;
typedef __attribute__((address_space(3))) u32 as3_u32;

#define E_DIM 512
#define L_DIM 100
#define Y_SZ  3200            // 32*100
#define LG_OFF 3200

__device__ __forceinline__ u16 f2bf(float f) {
  union { float f; u32 u; } v; v.f = f;
  u32 u = v.u;
  u32 r = u + 0x7fffu + ((u >> 16) & 1u);   // round-to-nearest-even
  return (u16)(r >> 16);
}

// ---------------- pre-kernel 1: c_emb f32 -> swizzled bf16 tile image -------
// Tile (mt, kt): 128 rows (bc) x 64 cols (e). ushort idx within tile:
//   r*64 + (c ^ ((r&7)<<3))   (XOR swizzle, 8-elem granularity -> 16B chunks)
__global__ __launch_bounds__(256) void conv_a_kernel(const float* __restrict__ src,
                                                     u16* __restrict__ dst) {
  int g = blockIdx.x * 256 + threadIdx.x;       // 131072 threads
  int base = g << 3;                             // 8 elems each
  int bc = base >> 9;
  int e  = base & 511;
  const float4* p = (const float4*)(src + base);
  float4 v0 = p[0];
  float4 v1 = p[1];
  union { u16 h[8]; uint4 q; } u;
  u.h[0]=f2bf(v0.x); u.h[1]=f2bf(v0.y); u.h[2]=f2bf(v0.z); u.h[3]=f2bf(v0.w);
  u.h[4]=f2bf(v1.x); u.h[5]=f2bf(v1.y); u.h[6]=f2bf(v1.z); u.h[7]=f2bf(v1.w);
  int mt = bc >> 7, kt = e >> 6, r = bc & 127, c = e & 63;
  int idx = (mt*8 + kt)*8192 + r*64 + (c ^ ((r & 7) << 3));
  *(uint4*)(dst + idx) = u.q;
}

// ---------------- pre-kernel 2: W1[l][e][h] -> W1T[l][h][e] bf16 tiles ------
// Dest tile (l, ht128, kt): 128 rows (h) x 64 cols (e), same swizzle as A.
__global__ __launch_bounds__(256) void conv_w_kernel(const float* __restrict__ W1,
                                                     u16* __restrict__ dst) {
  __shared__ float T[64][65];                    // [e_local][h_local], +1 pad
  int blk = blockIdx.x;                          // 100*64 = 6400
  int l = blk >> 6;
  int rem = blk & 63;
  int et = rem >> 3, ht = rem & 7;               // 64x64 tile of (e,h)
  int tid = threadIdx.x;
  int e0 = et*64, h0 = ht*64;
  const float* basep = W1 + (size_t)l * (E_DIM*E_DIM);
  int erow = tid >> 4;                           // 0..15
  int hq = (tid & 15) * 4;                       // 0..60
  #pragma unroll
  for (int i = 0; i < 4; ++i) {
    int e = erow + i*16;
    float4 v = *(const float4*)(basep + (size_t)(e0 + e)*E_DIM + h0 + hq);
    T[e][hq+0] = v.x; T[e][hq+1] = v.y; T[e][hq+2] = v.z; T[e][hq+3] = v.w;
  }
  __syncthreads();
  int rl_h = tid >> 3;                           // 0..31
  int c0 = (tid & 7) * 8;                        // e_local chunk
  size_t tbase = ((size_t)(l*4 + (ht >> 1))*8 + et) * 8192;
  #pragma unroll
  for (int p = 0; p < 2; ++p) {
    int r_local = p*32 + rl_h;                   // h within 64-tile
    union { u16 h[8]; uint4 q; } u;
    #pragma unroll
    for (int j = 0; j < 8; ++j) u.h[j] = f2bf(T[c0 + j][r_local]);
    int r = ((ht & 1) << 6) + r_local;           // h within 128-row dest tile
    size_t idx = tbase + r*64 + (c0 ^ ((r & 7) << 3));
    *(uint4*)(dst + idx) = u.q;
  }
}

// ---------------- main fused GEMM ------------------------------------------
// Block: (mt, l) via XCD-chunk-swizzled 1D grid. 512 thr = 8 waves (2Mx4N),
// wave tile 64x32. 128 bc-rows x 128 h-cols per h-block, 4 h-blocks, K=512 in
// 8x64 double-buffered LDS steps via global_load_lds.
__global__ __launch_bounds__(512, 4) void gemm_kernel(
    const u16* __restrict__ Aws, const u16* __restrict__ Wws,
    const float* __restrict__ c_pred, const float* __restrict__ b1,
    const float* __restrict__ W2, const float* __restrict__ b2,
    float* __restrict__ out)
{
  __shared__ __align__(16) u16 As[2][8192];      // 32 KB
  __shared__ __align__(16) u16 Bs[2][8192];      // 32 KB  (total 64 KB)

  // XCD swizzle: 1600 blocks, 1600%8==0 -> bijective chunk map.
  const int wg  = blockIdx.x;
  const int swz = (wg & 7) * 200 + (wg >> 3);
  const int l   = swz >> 4;                      // 0..99
  const int mt  = swz & 15;                      // 0..15
  const int tid = threadIdx.x;
  const int wid = tid >> 6;                      // 0..7
  const int lane = tid & 63;
  const int wr = wid >> 2;                       // wave row (0..1) -> 64 rows
  const int wc = wid & 3;                        // wave col (0..3) -> 32 cols
  const int lr = lane & 15;                      // M-row / N-col within 16
  const int lgp = lane >> 4;                     // k-group 0..3

  float wacc[4][4];
  #pragma unroll
  for (int m = 0; m < 4; ++m)
    #pragma unroll
    for (int r = 0; r < 4; ++r) wacc[m][r] = 0.f;

  auto stage = [&](int buf, int hb, int kt) {
    const u16* asrc = Aws + (mt*8 + kt)*8192;
    const u16* bsrc = Wws + ((l*4 + hb)*8 + kt)*8192;
    #pragma unroll
    for (int i = 0; i < 2; ++i) {
      int chunk = wid*2 + i;                     // 16 x 1KB chunks per tile
      int uoff = chunk*512;                      // ushort offset (wave-uniform)
      int goff = uoff + lane*8;                  // per-lane 16B
      __builtin_amdgcn_global_load_lds((as1_u32*)(asrc + goff),
                                       (as3_u32*)(&As[buf][uoff]), 16, 0, 0);
      __builtin_amdgcn_global_load_lds((as1_u32*)(bsrc + goff),
                                       (as3_u32*)(&Bs[buf][uoff]), 16, 0, 0);
    }
  };

  stage(0, 0, 0);
  __syncthreads();                               // drains vmcnt before barrier
  int cur = 0;
  const f32x4 zero4 = {0.f, 0.f, 0.f, 0.f};

  for (int hb = 0; hb < 4; ++hb) {
    f32x4 acc[4][2];
    #pragma unroll
    for (int mi = 0; mi < 4; ++mi)
      #pragma unroll
      for (int ni = 0; ni < 2; ++ni) acc[mi][ni] = zero4;

    for (int kt = 0; kt < 8; ++kt) {
      int nkt = kt + 1, nhb = hb;
      if (nkt == 8) { nkt = 0; ++nhb; }
      if (nhb < 4) stage(cur ^ 1, nhb, nkt);     // prefetch overlaps compute

      #pragma unroll
      for (int ks = 0; ks < 2; ++ks) {
        short8 af[4], bfr[2];
        #pragma unroll
        for (int mi = 0; mi < 4; ++mi) {
          int row = wr*64 + mi*16 + lr;
          int col = ks*32 + lgp*8;
          af[mi] = *(const short8*)&As[cur][row*64 + (col ^ ((row & 7) << 3))];
        }
        #pragma unroll
        for (int ni = 0; ni < 2; ++ni) {
          int row = wc*32 + ni*16 + lr;
          int col = ks*32 + lgp*8;
          bfr[ni] = *(const short8*)&Bs[cur][row*64 + (col ^ ((row & 7) << 3))];
        }
        #pragma unroll
        for (int mi = 0; mi < 4; ++mi)
          #pragma unroll
          for (int ni = 0; ni < 2; ++ni)
            acc[mi][ni] = __builtin_amdgcn_mfma_f32_16x16x32_bf16(
                af[mi], bfr[ni], acc[mi][ni], 0, 0, 0);
      }
      __syncthreads();                           // next buffer ready after this
      cur ^= 1;
    }

    // fused epilogue for this h-block: bias + ReLU + dot(W2), lane-local.
    // C/D layout (m89): col = lane&15, row = (lane>>4)*4 + reg.
    #pragma unroll
    for (int ni = 0; ni < 2; ++ni) {
      int h = hb*128 + wc*32 + ni*16 + lr;
      float b1v = b1[l*E_DIM + h];
      float w2v = W2[l*E_DIM + h];
      #pragma unroll
      for (int mi = 0; mi < 4; ++mi)
        #pragma unroll
        for (int r = 0; r < 4; ++r) {
          float v = acc[mi][ni][r] + b1v;
          v = fmaxf(v, 0.f);
          wacc[mi][r] = fmaf(v, w2v, wacc[mi][r]);
        }
    }
  }

  // reduce wacc over the 16 column-lanes (cols live in lane&15)
  #pragma unroll
  for (int m = 0; m < 4; ++m)
    #pragma unroll
    for (int r = 0; r < 4; ++r) {
      float s = wacc[m][r];
      s += __shfl_xor(s, 1);
      s += __shfl_xor(s, 2);
      s += __shfl_xor(s, 4);
      s += __shfl_xor(s, 8);
      wacc[m][r] = s;
    }

  float (*w_part)[128] = (float(*)[128])&As[0][0];  // reuse LDS (compute done)
  if (lr == 0) {
    #pragma unroll
    for (int m = 0; m < 4; ++m)
      #pragma unroll
      for (int r = 0; r < 4; ++r)
        w_part[wc][wr*64 + m*16 + lgp*4 + r] = wacc[m][r];
  }
  __syncthreads();

  if (tid < 128) {
    int bcg = mt*128 + tid;
    float w = w_part[0][tid] + w_part[1][tid] + w_part[2][tid] + w_part[3][tid]
            + b2[l];
    float lgt = w * c_pred[bcg];
    out[LG_OFF + bcg*L_DIM + l] = lgt;
    float s = lgt;
    s += __shfl_down(s, 32);
    s += __shfl_down(s, 16);
    s += __shfl_down(s, 8);
    s += __shfl_down(s, 4);
    s += __shfl_down(s, 2);
    s += __shfl_down(s, 1);
    if (lane == 0) out[(bcg >> 6)*L_DIM + l] = s;   // y[b,l]
  }
}

// ---------------- fallback (ws too small): correct fp32 path ---------------
__global__ __launch_bounds__(256) void naive_kernel(
    const float* __restrict__ c_emb, const float* __restrict__ c_pred,
    const float* __restrict__ W1, const float* __restrict__ b1,
    const float* __restrict__ W2, const float* __restrict__ b2,
    float* __restrict__ out)
{
  __shared__ float a_lds[16][512];
  __shared__ float wsum[4][16];
  int l = blockIdx.y;
  int rt = blockIdx.x;                           // 128 tiles of 16 rows
  int tid = threadIdx.x, lane = tid & 63, wid = tid >> 6;
  int row0 = rt * 16;
  #pragma unroll
  for (int i = 0; i < 8; ++i) {
    int flat = i*1024 + tid*4;
    int r = flat >> 9, e = flat & 511;
    *(float4*)&a_lds[r][e] = *(const float4*)&c_emb[(size_t)(row0 + r)*E_DIM + e];
  }
  __syncthreads();
  int h0 = tid, h1 = tid + 256;
  const float* w1b = W1 + (size_t)l * (E_DIM*E_DIM);
  float acc0[16], acc1[16];
  #pragma unroll
  for (int r = 0; r < 16; ++r) { acc0[r] = 0.f; acc1[r] = 0.f; }
  for (int e = 0; e < E_DIM; ++e) {
    float wa = w1b[(size_t)e*E_DIM + h0];
    float wb = w1b[(size_t)e*E_DIM + h1];
    #pragma unroll
    for (int r = 0; r < 16; ++r) {
      float a = a_lds[r][e];
      acc0[r] = fmaf(a, wa, acc0[r]);
      acc1[r] = fmaf(a, wb, acc1[r]);
    }
  }
  float b1a = b1[l*E_DIM + h0], b1c = b1[l*E_DIM + h1];
  float w2a = W2[l*E_DIM + h0], w2c = W2[l*E_DIM + h1];
  float part[16];
  #pragma unroll
  for (int r = 0; r < 16; ++r) {
    float v0 = fmaxf(acc0[r] + b1a, 0.f) * w2a;
    float v1 = fmaxf(acc1[r] + b1c, 0.f) * w2c;
    part[r] = v0 + v1;
  }
  #pragma unroll
  for (int r = 0; r < 16; ++r) {
    float s = part[r];
    s += __shfl_down(s, 32); s += __shfl_down(s, 16); s += __shfl_down(s, 8);
    s += __shfl_down(s, 4);  s += __shfl_down(s, 2);  s += __shfl_down(s, 1);
    if (lane == 0) wsum[wid][r] = s;
  }
  __syncthreads();
  if (tid < 16) {
    float w = wsum[0][tid] + wsum[1][tid] + wsum[2][tid] + wsum[3][tid] + b2[l];
    int bc = row0 + tid;
    float lgt = w * c_pred[bc];
    out[LG_OFF + bc*L_DIM + l] = lgt;
    atomicAdd(&out[(bc >> 6)*L_DIM + l], lgt);
  }
}

extern "C" void kernel_launch(void* const* d_in, const int* in_sizes, int n_in,
                              void* d_out, int out_size, void* d_ws, size_t ws_size,
                              hipStream_t stream) {
  const float* c_emb  = (const float*)d_in[0];
  const float* c_pred = (const float*)d_in[1];
  const float* W1     = (const float*)d_in[2];
  const float* b1     = (const float*)d_in[3];
  const float* W2     = (const float*)d_in[4];
  const float* b2     = (const float*)d_in[5];
  float* out = (float*)d_out;

  const size_t nA = 1048576;       // 32*64*512
  const size_t nW = 26214400;      // 100*512*512
  const size_t need = 2*nA + 2*nW; // bf16 copies: ~54.5 MB

  if (ws_size >= need) {
    u16* Aws = (u16*)d_ws;
    u16* Wws = (u16*)d_ws + nA;
    conv_a_kernel<<<512, 256, 0, stream>>>(c_emb, Aws);
    conv_w_kernel<<<6400, 256, 0, stream>>>(W1, Wws);
    gemm_kernel<<<1600, 512, 0, stream>>>(Aws, Wws, c_pred, b1, W2, b2, out);
  } else {
    hipMemsetAsync(out, 0, Y_SZ*sizeof(float), stream);  // y accumulated via atomics
    naive_kernel<<<dim3(128, 100), 256, 0, stream>>>(c_emb, c_pred, W1, b1, W2, b2, out);
  }
}